// Round 6
// baseline (20.029 us; speedup 1.0000x reference)
//
#include <hip/hip_runtime.h>
#include <math.h>

#define LN_EPS 1e-5f

// ws: partial col-sums, [128 row-groups][256] floats (real 0..127, imag 128..255).
// Fully rewritten by k_vln before k_out reads it each call.

// ---------------------------------------------------------------------------
// Kernel 1: fused GEMM (v @ Wv^T) + per-row LayerNorm + 8-row column-sum.
// W is REGISTER-resident (thread = col x d-chunk, 8 float4s); only the 8
// x-rows are staged in LDS (swizzled, conflict-free). Uniform softmax makes
// the attention output the column-mean of LN'd V, so only V matters.
// ---------------------------------------------------------------------------
__global__ __launch_bounds__(512) void k_vln(
    const float* __restrict__ vr_in, const float* __restrict__ vi_in,
    const float* __restrict__ Wv,
    const float* __restrict__ vg, const float* __restrict__ vb,
    float* __restrict__ partial)
{
    const int gb  = blockIdx.x;   // 8-row group, 0..127
    const int tid = threadIdx.x;
    const int c   = tid >> 2;     // output col 0..127
    const int dc  = tid & 3;      // d-chunk 0..3 (32 floats each)

    __shared__ float4 s_x[2][8][32];   // [arr][row][swizzled d4 slot]
    __shared__ float  sred[8][8][4];   // [row][wave][sr,s2r,si,s2i]
    __shared__ float  sfin[8][4];

    // W fragment -> registers (one 64 KB L2 read per block, no LDS)
    float4 w[8];
    #pragma unroll
    for (int i = 0; i < 8; ++i)
        w[i] = *(const float4*)&Wv[c * 128 + dc * 32 + i * 4];

    // stage 8 rows of vr/vi; chunk d4 stored at slot (d4&7)*4 + (d4>>3) so
    // the 4 dc-lanes of a quarter-wave read distinct bank-sets.
    {
        const int arr = tid >> 8;
        const int row = (tid >> 5) & 7;
        const int d4  = tid & 31;
        const float* src = arr ? vi_in : vr_in;
        float4 v = *(const float4*)&src[(gb * 8 + row) * 128 + d4 * 4];
        s_x[arr][row][(d4 & 7) * 4 + (d4 >> 3)] = v;
    }
    __syncthreads();

    const int wv = tid >> 6;
    float dotr[8], doti[8];
    #pragma unroll
    for (int r = 0; r < 8; ++r) {
        float pr = 0.f, pi = 0.f;
        #pragma unroll
        for (int i = 0; i < 8; ++i) {
            float4 xr = s_x[0][r][i * 4 + dc];
            float4 xi = s_x[1][r][i * 4 + dc];
            pr += xr.x * w[i].x + xr.y * w[i].y + xr.z * w[i].z + xr.w * w[i].w;
            pi += xi.x * w[i].x + xi.y * w[i].y + xi.z * w[i].z + xi.w * w[i].w;
        }
        // combine the 4 d-chunks (adjacent lanes)
        pr += __shfl_xor(pr, 1); pr += __shfl_xor(pr, 2);
        pi += __shfl_xor(pi, 1); pi += __shfl_xor(pi, 2);
        dotr[r] = pr; doti[r] = pi;
        // LN stats: full-wave butterfly (4x duplication folded out later)
        float s1 = pr, s2 = pr * pr, s3 = pi, s4 = pi * pi;
        #pragma unroll
        for (int off = 32; off >= 1; off >>= 1) {
            s1 += __shfl_xor(s1, off);
            s2 += __shfl_xor(s2, off);
            s3 += __shfl_xor(s3, off);
            s4 += __shfl_xor(s4, off);
        }
        if ((tid & 63) == 0) {
            sred[r][wv][0] = s1; sred[r][wv][1] = s2;
            sred[r][wv][2] = s3; sred[r][wv][3] = s4;
        }
    }
    __syncthreads();
    if (tid < 32) {
        const int r = tid >> 2, comp = tid & 3;
        float s = 0.f;
        #pragma unroll
        for (int w8 = 0; w8 < 8; ++w8) s += sred[r][w8][comp];
        sfin[r][comp] = s;
    }
    __syncthreads();

    const float inv = 1.f / 512.f;   // 128 cols x 4 duplicate lanes
    float csr = 0.f, csi = 0.f;
    #pragma unroll
    for (int r = 0; r < 8; ++r) {
        float mur  = sfin[r][0] * inv;
        float rstr = rsqrtf(sfin[r][1] * inv - mur * mur + LN_EPS);
        float mui  = sfin[r][2] * inv;
        float rsti = rsqrtf(sfin[r][3] * inv - mui * mui + LN_EPS);
        csr += (dotr[r] - mur) * rstr;
        csi += (doti[r] - mui) * rsti;
    }
    if (dc == 0) {   // sum of 8 LN'd rows: g * sum(z) + 8*b
        float gc = vg[c], bc = vb[c];
        partial[gb * 256 + c]       = csr * gc + 8.f * bc;
        partial[gb * 256 + 128 + c] = csi * gc + 8.f * bc;
    }
}

// ---------------------------------------------------------------------------
// Kernel 2: per batch, sum the 64 row-group partials, LayerNorm the summed
// column vector (LN is scale-invariant so /512 is unnecessary), broadcast
// to 16 q-rows per block. Grid 64 = b(2) x chunk(32).
// ---------------------------------------------------------------------------
__global__ __launch_bounds__(256) void k_out(
    const float* __restrict__ partial,
    const float* __restrict__ on_g, const float* __restrict__ on_b,
    float* __restrict__ out)
{
    const int tid   = threadIdx.x;   // = arr*128 + d
    const int b     = blockIdx.x >> 5;
    const int chunk = blockIdx.x & 31;
    const int arr   = tid >> 7;      // 0 = real, 1 = imag
    const int d     = tid & 127;

    float s = 0.f;
    const float* p = partial + b * 64 * 256 + tid;
    #pragma unroll
    for (int g = 0; g < 64; ++g) s += p[g * 256];

    float s1 = s, s2 = s * s;
    #pragma unroll
    for (int off = 32; off >= 1; off >>= 1) {
        s1 += __shfl_xor(s1, off);
        s2 += __shfl_xor(s2, off);
    }
    __shared__ float sred[4][2];
    if ((tid & 63) == 0) { sred[tid >> 6][0] = s1; sred[tid >> 6][1] = s2; }
    __syncthreads();
    const float inv = 1.f / 128.f;
    float tot  = (sred[arr * 2][0] + sred[arr * 2 + 1][0]) * inv;
    float tot2 = (sred[arr * 2][1] + sred[arr * 2 + 1][1]) * inv;
    float y = (s - tot) * rsqrtf(tot2 - tot * tot + LN_EPS) * on_g[d] + on_b[d];

    const int rbase = b * 512 + chunk * 16;
    float* o = out + arr * 131072 + rbase * 128 + d;
    #pragma unroll
    for (int rr = 0; rr < 16; ++rr) o[rr * 128] = y;
}

extern "C" void kernel_launch(void* const* d_in, const int* in_sizes, int n_in,
                              void* d_out, int out_size, void* d_ws, size_t ws_size,
                              hipStream_t stream)
{
    const float* v_r = (const float*)d_in[4];
    const float* v_i = (const float*)d_in[5];
    const float* Wv  = (const float*)d_in[8];
    const float* vg  = (const float*)d_in[13];
    const float* vb  = (const float*)d_in[14];
    const float* og  = (const float*)d_in[15];
    const float* ob  = (const float*)d_in[16];

    float* ws  = (float*)d_ws;
    float* out = (float*)d_out;

    k_vln<<<128, 512, 0, stream>>>(v_r, v_i, Wv, vg, vb, ws);
    k_out<<<64, 256, 0, stream>>>(ws, og, ob, out);
}

// Round 7
// 16.799 us; speedup vs baseline: 1.1922x; 1.1922x over previous
//
#include <hip/hip_runtime.h>
#include <math.h>

#define LN_EPS 1e-5f

// ws: partial col-sums, [128 row-groups][256] floats (real 0..127, imag 128..255).
// Groups 0..63 = batch 0, 64..127 = batch 1. Fully rewritten every call.

// ---------------------------------------------------------------------------
// Kernel 1: fused GEMM (v @ Wv^T) + per-row LayerNorm + 8-row column-sum.
// 128 blocks x 256 threads, 8 rows/block. W register-resident per thread
// (col c, d-half h -> 16 float4). x staged in LDS, read as wave-uniform
// broadcasts. LN stats via 16-col-per-thread partial sums + 3-step shfl
// (128 threads only). No per-row butterfly storms (the R6 mistake).
// Uniform softmax (coherence==0 in fp32) makes the attention output the
// column-mean of LN'd V rows, so only the V path matters.
// ---------------------------------------------------------------------------
__global__ __launch_bounds__(256) void k_vln(
    const float* __restrict__ vr_in, const float* __restrict__ vi_in,
    const float* __restrict__ Wv,
    const float* __restrict__ vg, const float* __restrict__ vb,
    float* __restrict__ partial)
{
    const int gb  = blockIdx.x;   // 8-row group, 0..127
    const int tid = threadIdx.x;
    const int c   = tid & 127;    // output col
    const int h   = tid >> 7;     // d-half (0: d<64, 1: d>=64)

    __shared__ float4 s_x[2][8][32];      // [arr][row][d4] plain, 8 KB
    __shared__ float  s_y[2][8][2][128];  // [arr][row][half][col], 16 KB
    __shared__ float2 s_stat[2][8];       // (mu, rstd) per (arr,row)

    // W fragment -> 16 float4 VGPRs (one 64 KB L2 read per block)
    float4 w[16];
    const float* wp = Wv + c * 128 + h * 64;
    #pragma unroll
    for (int i = 0; i < 16; ++i) w[i] = *(const float4*)&wp[i * 4];

    // stage 8 rows x 2 arrays of x (coalesced)
    #pragma unroll
    for (int it = 0; it < 2; ++it) {
        int fi  = it * 256 + tid;         // 0..511
        int a   = fi >> 8;
        int row = (fi >> 5) & 7;
        int d4  = fi & 31;
        const float* src = a ? vi_in : vr_in;
        s_x[a][row][d4] = *(const float4*)&src[(gb * 8 + row) * 128 + d4 * 4];
    }
    __syncthreads();

    // Phase A: half-dots. x reads are wave-uniform broadcasts (h uniform per wave).
    #pragma unroll
    for (int r = 0; r < 8; ++r) {
        #pragma unroll
        for (int a = 0; a < 2; ++a) {
            float p = 0.f;
            #pragma unroll
            for (int i = 0; i < 16; ++i) {
                float4 x = s_x[a][r][h * 16 + i];
                p += x.x * w[i].x + x.y * w[i].y + x.z * w[i].z + x.w * w[i].w;
            }
            s_y[a][r][h][c] = p;
        }
    }
    __syncthreads();

    // Phase B1: row stats. 128 threads: (a, r, cq) sums 16 cols, 3-step shfl.
    if (tid < 128) {
        const int a  = tid >> 6;
        const int r  = (tid >> 3) & 7;
        const int cq = tid & 7;
        float s1 = 0.f, s2 = 0.f;
        #pragma unroll
        for (int j = 0; j < 4; ++j) {
            float4 y0 = *(const float4*)&s_y[a][r][0][cq * 16 + j * 4];
            float4 y1 = *(const float4*)&s_y[a][r][1][cq * 16 + j * 4];
            float yx = y0.x + y1.x, yy = y0.y + y1.y;
            float yz = y0.z + y1.z, yw = y0.w + y1.w;
            s1 += yx + yy + yz + yw;
            s2 += yx * yx + yy * yy + yz * yz + yw * yw;
        }
        s1 += __shfl_xor(s1, 1); s2 += __shfl_xor(s2, 1);
        s1 += __shfl_xor(s1, 2); s2 += __shfl_xor(s2, 2);
        s1 += __shfl_xor(s1, 4); s2 += __shfl_xor(s2, 4);
        if (cq == 0) {
            const float inv = 1.f / 128.f;
            float mu = s1 * inv;
            float rstd = rsqrtf(s2 * inv - mu * mu + LN_EPS);
            s_stat[a][r] = make_float2(mu, rstd);
        }
    }
    __syncthreads();

    // Phase B2: column-sum of the 8 LayerNorm'd rows; fold g,b once.
    {
        const int a = tid >> 7;           // reuse h slot as array index
        float cs = 0.f;
        #pragma unroll
        for (int r = 0; r < 8; ++r) {
            float y = s_y[a][r][0][c] + s_y[a][r][1][c];
            float2 st = s_stat[a][r];
            cs += (y - st.x) * st.y;
        }
        partial[gb * 256 + a * 128 + c] = cs * vg[c] + 8.f * vb[c];
    }
}

// ---------------------------------------------------------------------------
// Kernel 2: per batch, sum the 64 row-group partials, LayerNorm the summed
// column vector (LN is scale-invariant so /512 is unnecessary), broadcast
// to 16 q-rows per block. Grid 64 = b(2) x chunk(32).
// ---------------------------------------------------------------------------
__global__ __launch_bounds__(256) void k_out(
    const float* __restrict__ partial,
    const float* __restrict__ on_g, const float* __restrict__ on_b,
    float* __restrict__ out)
{
    const int tid   = threadIdx.x;   // = arr*128 + d
    const int b     = blockIdx.x >> 5;
    const int chunk = blockIdx.x & 31;
    const int arr   = tid >> 7;      // 0 = real, 1 = imag
    const int d     = tid & 127;

    float s = 0.f;
    const float* p = partial + b * 64 * 256 + tid;
    #pragma unroll
    for (int g = 0; g < 64; ++g) s += p[g * 256];

    float s1 = s, s2 = s * s;
    #pragma unroll
    for (int off = 32; off >= 1; off >>= 1) {
        s1 += __shfl_xor(s1, off);
        s2 += __shfl_xor(s2, off);
    }
    __shared__ float sred[4][2];
    if ((tid & 63) == 0) { sred[tid >> 6][0] = s1; sred[tid >> 6][1] = s2; }
    __syncthreads();
    const float inv = 1.f / 128.f;
    float tot  = (sred[arr * 2][0] + sred[arr * 2 + 1][0]) * inv;
    float tot2 = (sred[arr * 2][1] + sred[arr * 2 + 1][1]) * inv;
    float y = (s - tot) * rsqrtf(tot2 - tot * tot + LN_EPS) * on_g[d] + on_b[d];

    const int rbase = b * 512 + chunk * 16;
    float* o = out + arr * 131072 + rbase * 128 + d;
    #pragma unroll
    for (int rr = 0; rr < 16; ++rr) o[rr * 128] = y;
}

extern "C" void kernel_launch(void* const* d_in, const int* in_sizes, int n_in,
                              void* d_out, int out_size, void* d_ws, size_t ws_size,
                              hipStream_t stream)
{
    const float* v_r = (const float*)d_in[4];
    const float* v_i = (const float*)d_in[5];
    const float* Wv  = (const float*)d_in[8];
    const float* vg  = (const float*)d_in[13];
    const float* vb  = (const float*)d_in[14];
    const float* og  = (const float*)d_in[15];
    const float* ob  = (const float*)d_in[16];

    float* ws  = (float*)d_ws;
    float* out = (float*)d_out;

    k_vln<<<128, 256, 0, stream>>>(v_r, v_i, Wv, vg, vb, ws);
    k_out<<<64, 256, 0, stream>>>(ws, og, ob, out);
}